// Round 1
// baseline (641.544 us; speedup 1.0000x reference)
//
#include <hip/hip_runtime.h>
#include <math.h>

#define BB 4
#define NN 8192
#define MM 2048
#define CC 64
#define KNB 32
#define CIN 67   // 3 + CC
#define H1 64
#define H2 128

// ---------------- init: zero per-batch maxnorm cells ----------------
__global__ void init_kernel(int* maxnorm) {
    if (threadIdx.x < BB) maxnorm[threadIdx.x] = 0;
}

// ---------------- kNN: one block per anchor ----------------
__global__ __launch_bounds__(256, 4) void knn_kernel(
    const float* __restrict__ coord, const float* __restrict__ anchor_coord,
    int* __restrict__ idxbuf, int* __restrict__ maxnorm)
{
    __shared__ float d2s[256 * 33];   // padded [chunk][33]
    __shared__ float cmin[256];
    __shared__ int   carg[256];
    __shared__ float rd[4];
    __shared__ int   ri[4];
    __shared__ int   sel_s[KNB];

    const int anchor = blockIdx.x;
    const int b  = anchor >> 11;          // / MM
    const int mi = anchor & (MM - 1);
    const int tid = threadIdx.x;

    const float ax = anchor_coord[(b * MM + mi) * 3 + 0];
    const float ay = anchor_coord[(b * MM + mi) * 3 + 1];
    const float az = anchor_coord[(b * MM + mi) * 3 + 2];
    const float a2 = __fadd_rn(__fadd_rn(__fmul_rn(ax, ax), __fmul_rn(ay, ay)), __fmul_rn(az, az));

    const float* cb = coord + (size_t)b * NN * 3;

    // distances (replicate reference formula, no FMA contraction)
    for (int i = tid; i < NN; i += 256) {
        float cx = cb[i * 3 + 0], cy = cb[i * 3 + 1], cz = cb[i * 3 + 2];
        float c2 = __fadd_rn(__fadd_rn(__fmul_rn(cx, cx), __fmul_rn(cy, cy)), __fmul_rn(cz, cz));
        float dt = __fadd_rn(__fadd_rn(__fmul_rn(ax, cx), __fmul_rn(ay, cy)), __fmul_rn(az, cz));
        float d2 = __fadd_rn(__fsub_rn(a2, __fmul_rn(2.0f, dt)), c2);
        d2s[(i >> 5) * 33 + (i & 31)] = d2;
    }
    __syncthreads();

    // per-chunk min (chunk = 32 points, one per thread)
    {
        float bd = INFINITY; int bi = NN;
        const int base = tid * 33;
        #pragma unroll
        for (int j = 0; j < 32; j++) {
            float v = d2s[base + j];
            if (v < bd) { bd = v; bi = tid * 32 + j; }
        }
        cmin[tid] = bd; carg[tid] = bi;
    }
    __syncthreads();

    // 32 rounds of hierarchical argmin (tie-break: lower global index)
    for (int it = 0; it < KNB; it++) {
        float v = cmin[tid]; int gi = carg[tid];
        #pragma unroll
        for (int off = 32; off; off >>= 1) {
            float ov = __shfl_xor(v, off);
            int   og = __shfl_xor(gi, off);
            if (ov < v || (ov == v && og < gi)) { v = ov; gi = og; }
        }
        if ((tid & 63) == 0) { rd[tid >> 6] = v; ri[tid >> 6] = gi; }
        __syncthreads();
        float fv = rd[0]; int fgi = ri[0];
        #pragma unroll
        for (int ww = 1; ww < 4; ww++) {
            float wv = rd[ww]; int wg = ri[ww];
            if (wv < fv || (wv == fv && wg < fgi)) { fv = wv; fgi = wg; }
        }
        const int wc = fgi >> 5;
        if (tid == wc) {           // owner removes winner, rescans its chunk
            d2s[wc * 33 + (fgi & 31)] = INFINITY;
            float nb = INFINITY; int nbi = NN;
            #pragma unroll
            for (int j = 0; j < 32; j++) {
                float x = d2s[wc * 33 + j];
                if (x < nb) { nb = x; nbi = wc * 32 + j; }
            }
            cmin[wc] = nb; carg[wc] = nbi;
        }
        if (tid == 0) sel_s[it] = fgi;
        __syncthreads();
    }

    // write indices; per-batch max ||delta||
    float nrm = 0.0f;
    if (tid < KNB) {
        int j = sel_s[tid];
        idxbuf[anchor * KNB + tid] = j;
        float dx = __fsub_rn(cb[j * 3 + 0], ax);
        float dy = __fsub_rn(cb[j * 3 + 1], ay);
        float dz = __fsub_rn(cb[j * 3 + 2], az);
        nrm = sqrtf(dx * dx + dy * dy + dz * dz);
    }
    if (tid < 64) {
        #pragma unroll
        for (int off = 32; off; off >>= 1) nrm = fmaxf(nrm, __shfl_xor(nrm, off));
        if (tid == 0) atomicMax(&maxnorm[b], __float_as_int(nrm));  // non-neg floats: int cmp == float cmp
    }
}

// ---------------- fused gather + MLP + maxpool: one block per anchor ----------------
__global__ __launch_bounds__(256, 2) void mlp_kernel(
    const float* __restrict__ feat, const float* __restrict__ coord,
    const float* __restrict__ anchor_feat, const float* __restrict__ anchor_coord,
    const float* __restrict__ W1, const float* __restrict__ b1,
    const float* __restrict__ g1, const float* __restrict__ be1,
    const float* __restrict__ W2, const float* __restrict__ b2,
    const float* __restrict__ g2, const float* __restrict__ be2,
    const int* __restrict__ maxnorm, const int* __restrict__ idxbuf,
    float* __restrict__ out)
{
    __shared__ float W1s[CIN * H1];
    __shared__ float W2s[H1 * H2];
    __shared__ __align__(16) float xst[CIN * KNB];   // x transposed: [j][k]
    __shared__ __align__(16) float h1t[H1 * 36];     // h1 transposed: [ch][k], pad to 36
    __shared__ float b1s[H1], g1s[H1], be1s[H1];
    __shared__ float b2s[H2], g2s[H2], be2s[H2];
    __shared__ int   sel[KNB];
    __shared__ float pmax[4 * H2];

    const int anchor = blockIdx.x;
    const int b  = anchor >> 11;
    const int mi = anchor & (MM - 1);
    const int tid = threadIdx.x;

    for (int t = tid; t < CIN * H1; t += 256) W1s[t] = W1[t];
    for (int t = tid; t < H1 * H2; t += 256) W2s[t] = W2[t];
    if (tid < H1) { b1s[tid] = b1[tid]; g1s[tid] = g1[tid]; be1s[tid] = be1[tid]; }
    else if (tid < H1 + H2) { int c = tid - H1; b2s[c] = b2[c]; g2s[c] = g2[c]; be2s[c] = be2[c]; }
    if (tid < KNB) sel[tid] = idxbuf[anchor * KNB + tid];
    __syncthreads();

    const float mn = __int_as_float(maxnorm[b]);

    // build x^T: rows j (3 delta + 64 feat), cols k (neighbors)
    for (int t = tid; t < CIN * KNB; t += 256) {
        int j = t >> 5, k = t & 31;
        int nj = sel[k];
        float vv;
        if (j < 3) {
            float d = __fsub_rn(coord[((size_t)b * NN + nj) * 3 + j],
                                anchor_coord[((size_t)b * MM + mi) * 3 + j]);
            vv = __fdiv_rn(d, mn);
        } else {
            vv = feat[((size_t)b * NN + nj) * CC + (j - 3)]
               - anchor_feat[((size_t)b * MM + mi) * CC + (j - 3)];
        }
        xst[t] = vv;
    }
    __syncthreads();

    const int w = tid >> 6, lane = tid & 63;
    const int k0 = w * 8;   // this wave owns rows k0..k0+7; channel = lane

    // ---- stage 1: h1 = relu(LN(x @ W1 + b1)) ----
    float acc[8];
    #pragma unroll
    for (int kk = 0; kk < 8; kk++) acc[kk] = b1s[lane];
    for (int j = 0; j < CIN; j++) {
        float wv = W1s[j * H1 + lane];
        const float4 xa = *(const float4*)&xst[j * KNB + k0];
        const float4 xb = *(const float4*)&xst[j * KNB + k0 + 4];
        acc[0] = fmaf(xa.x, wv, acc[0]);
        acc[1] = fmaf(xa.y, wv, acc[1]);
        acc[2] = fmaf(xa.z, wv, acc[2]);
        acc[3] = fmaf(xa.w, wv, acc[3]);
        acc[4] = fmaf(xb.x, wv, acc[4]);
        acc[5] = fmaf(xb.y, wv, acc[5]);
        acc[6] = fmaf(xb.z, wv, acc[6]);
        acc[7] = fmaf(xb.w, wv, acc[7]);
    }
    #pragma unroll
    for (int kk = 0; kk < 8; kk++) {
        float vv = acc[kk];
        float s = vv, s2 = vv * vv;
        #pragma unroll
        for (int off = 32; off; off >>= 1) { s += __shfl_xor(s, off); s2 += __shfl_xor(s2, off); }
        float mu  = s  * (1.0f / H1);
        float var = s2 * (1.0f / H1) - mu * mu;
        float r = rsqrtf(var + 1e-6f);
        float y = fmaf((vv - mu) * r, g1s[lane], be1s[lane]);
        h1t[lane * 36 + k0 + kk] = fmaxf(y, 0.0f);
    }
    __syncthreads();

    // ---- stage 2: h2 = relu(LN(h1 @ W2 + b2)), maxpool over k ----
    float a[16];
    #pragma unroll
    for (int kk = 0; kk < 8; kk++) { a[kk] = b2s[lane]; a[8 + kk] = b2s[lane + 64]; }
    for (int j = 0; j < H1; j++) {
        float w0 = W2s[j * H2 + lane];
        float w1 = W2s[j * H2 + lane + 64];
        const float4 ha = *(const float4*)&h1t[j * 36 + k0];
        const float4 hb = *(const float4*)&h1t[j * 36 + k0 + 4];
        a[0] = fmaf(ha.x, w0, a[0]);   a[8]  = fmaf(ha.x, w1, a[8]);
        a[1] = fmaf(ha.y, w0, a[1]);   a[9]  = fmaf(ha.y, w1, a[9]);
        a[2] = fmaf(ha.z, w0, a[2]);   a[10] = fmaf(ha.z, w1, a[10]);
        a[3] = fmaf(ha.w, w0, a[3]);   a[11] = fmaf(ha.w, w1, a[11]);
        a[4] = fmaf(hb.x, w0, a[4]);   a[12] = fmaf(hb.x, w1, a[12]);
        a[5] = fmaf(hb.y, w0, a[5]);   a[13] = fmaf(hb.y, w1, a[13]);
        a[6] = fmaf(hb.z, w0, a[6]);   a[14] = fmaf(hb.z, w1, a[14]);
        a[7] = fmaf(hb.w, w0, a[7]);   a[15] = fmaf(hb.w, w1, a[15]);
    }
    float mx0 = -INFINITY, mx1 = -INFINITY;
    #pragma unroll
    for (int kk = 0; kk < 8; kk++) {
        float a0 = a[kk], a1 = a[8 + kk];
        float s = a0 + a1, s2 = a0 * a0 + a1 * a1;
        #pragma unroll
        for (int off = 32; off; off >>= 1) { s += __shfl_xor(s, off); s2 += __shfl_xor(s2, off); }
        float mu  = s  * (1.0f / H2);
        float var = s2 * (1.0f / H2) - mu * mu;
        float r = rsqrtf(var + 1e-6f);
        float y0 = fmaxf(fmaf((a0 - mu) * r, g2s[lane],      be2s[lane]),      0.0f);
        float y1 = fmaxf(fmaf((a1 - mu) * r, g2s[lane + 64], be2s[lane + 64]), 0.0f);
        mx0 = fmaxf(mx0, y0);
        mx1 = fmaxf(mx1, y1);
    }
    pmax[w * H2 + lane]      = mx0;
    pmax[w * H2 + lane + 64] = mx1;
    __syncthreads();
    if (tid < H2) {
        float vv = pmax[tid];
        #pragma unroll
        for (int ww = 1; ww < 4; ww++) vv = fmaxf(vv, pmax[ww * H2 + tid]);
        out[(size_t)anchor * H2 + tid] = vv;
    }
}

extern "C" void kernel_launch(void* const* d_in, const int* in_sizes, int n_in,
                              void* d_out, int out_size, void* d_ws, size_t ws_size,
                              hipStream_t stream) {
    const float* feat         = (const float*)d_in[0];
    const float* coord        = (const float*)d_in[1];
    const float* anchor_feat  = (const float*)d_in[2];
    const float* anchor_coord = (const float*)d_in[3];
    const float* W1  = (const float*)d_in[4];
    const float* b1  = (const float*)d_in[5];
    const float* g1  = (const float*)d_in[6];
    const float* be1 = (const float*)d_in[7];
    const float* W2  = (const float*)d_in[8];
    const float* b2  = (const float*)d_in[9];
    const float* g2  = (const float*)d_in[10];
    const float* be2 = (const float*)d_in[11];
    float* out = (float*)d_out;

    int* maxn   = (int*)d_ws;        // 4 ints
    int* idxbuf = (int*)d_ws + 16;   // [BB*MM*KNB]

    init_kernel<<<1, 64, 0, stream>>>(maxn);
    knn_kernel<<<BB * MM, 256, 0, stream>>>(coord, anchor_coord, idxbuf, maxn);
    mlp_kernel<<<BB * MM, 256, 0, stream>>>(feat, coord, anchor_feat, anchor_coord,
                                            W1, b1, g1, be1, W2, b2, g2, be2,
                                            maxn, idxbuf, out);
}

// Round 5
// 568.692 us; speedup vs baseline: 1.1281x; 1.1281x over previous
//
#include <hip/hip_runtime.h>
#include <math.h>

#define BB 4
#define NN 8192
#define MM 2048
#define CC 64
#define KNB 32
#define CIN 67   // 3 + CC
#define H1 64
#define H2 128

// ---------------- init: zero per-batch maxnorm cells ----------------
__global__ void init_kernel(int* maxnorm) {
    if (threadIdx.x < BB) maxnorm[threadIdx.x] = 0;
}

// ---------------- kNN: one block per anchor (byte-exact round-1 kernel, validated) ----------------
__global__ __launch_bounds__(256, 4) void knn_kernel(
    const float* __restrict__ coord, const float* __restrict__ anchor_coord,
    int* __restrict__ idxbuf, int* __restrict__ maxnorm)
{
    __shared__ float d2s[256 * 33];   // padded [chunk][33]
    __shared__ float cmin[256];
    __shared__ int   carg[256];
    __shared__ float rd[4];
    __shared__ int   ri[4];
    __shared__ int   sel_s[KNB];

    const int anchor = blockIdx.x;
    const int b  = anchor >> 11;          // / MM
    const int mi = anchor & (MM - 1);
    const int tid = threadIdx.x;

    const float ax = anchor_coord[(b * MM + mi) * 3 + 0];
    const float ay = anchor_coord[(b * MM + mi) * 3 + 1];
    const float az = anchor_coord[(b * MM + mi) * 3 + 2];
    const float a2 = __fadd_rn(__fadd_rn(__fmul_rn(ax, ax), __fmul_rn(ay, ay)), __fmul_rn(az, az));

    const float* cb = coord + (size_t)b * NN * 3;

    // distances (replicate reference formula, no FMA contraction)
    for (int i = tid; i < NN; i += 256) {
        float cx = cb[i * 3 + 0], cy = cb[i * 3 + 1], cz = cb[i * 3 + 2];
        float c2 = __fadd_rn(__fadd_rn(__fmul_rn(cx, cx), __fmul_rn(cy, cy)), __fmul_rn(cz, cz));
        float dt = __fadd_rn(__fadd_rn(__fmul_rn(ax, cx), __fmul_rn(ay, cy)), __fmul_rn(az, cz));
        float d2 = __fadd_rn(__fsub_rn(a2, __fmul_rn(2.0f, dt)), c2);
        d2s[(i >> 5) * 33 + (i & 31)] = d2;
    }
    __syncthreads();

    // per-chunk min (chunk = 32 points, one per thread)
    {
        float bd = INFINITY; int bi = NN;
        const int base = tid * 33;
        #pragma unroll
        for (int j = 0; j < 32; j++) {
            float v = d2s[base + j];
            if (v < bd) { bd = v; bi = tid * 32 + j; }
        }
        cmin[tid] = bd; carg[tid] = bi;
    }
    __syncthreads();

    // 32 rounds of hierarchical argmin (tie-break: lower global index)
    for (int it = 0; it < KNB; it++) {
        float v = cmin[tid]; int gi = carg[tid];
        #pragma unroll
        for (int off = 32; off; off >>= 1) {
            float ov = __shfl_xor(v, off);
            int   og = __shfl_xor(gi, off);
            if (ov < v || (ov == v && og < gi)) { v = ov; gi = og; }
        }
        if ((tid & 63) == 0) { rd[tid >> 6] = v; ri[tid >> 6] = gi; }
        __syncthreads();
        float fv = rd[0]; int fgi = ri[0];
        #pragma unroll
        for (int ww = 1; ww < 4; ww++) {
            float wv = rd[ww]; int wg = ri[ww];
            if (wv < fv || (wv == fv && wg < fgi)) { fv = wv; fgi = wg; }
        }
        const int wc = fgi >> 5;
        if (tid == wc) {           // owner removes winner, rescans its chunk
            d2s[wc * 33 + (fgi & 31)] = INFINITY;
            float nb = INFINITY; int nbi = NN;
            #pragma unroll
            for (int j = 0; j < 32; j++) {
                float x = d2s[wc * 33 + j];
                if (x < nb) { nb = x; nbi = wc * 32 + j; }
            }
            cmin[wc] = nb; carg[wc] = nbi;
        }
        if (tid == 0) sel_s[it] = fgi;
        __syncthreads();
    }

    // write indices; per-batch max ||delta||
    float nrm = 0.0f;
    if (tid < KNB) {
        int j = sel_s[tid];
        idxbuf[anchor * KNB + tid] = j;
        float dx = __fsub_rn(cb[j * 3 + 0], ax);
        float dy = __fsub_rn(cb[j * 3 + 1], ay);
        float dz = __fsub_rn(cb[j * 3 + 2], az);
        nrm = sqrtf(dx * dx + dy * dy + dz * dz);
    }
    if (tid < 64) {
        #pragma unroll
        for (int off = 32; off; off >>= 1) nrm = fmaxf(nrm, __shfl_xor(nrm, off));
        if (tid == 0) atomicMax(&maxnorm[b], __float_as_int(nrm));  // non-neg floats: int cmp == float cmp
    }
}

// ---------------- fused gather + MLP + maxpool: one block per anchor ----------------
// Weights read directly from global/L2 (no LDS staging): LDS 71.6KB -> ~20KB,
// occupancy 2 -> up to 6-8 blocks/CU. Numerics byte-identical to the staged version.
__global__ __launch_bounds__(256, 6) void mlp_kernel(
    const float* __restrict__ feat, const float* __restrict__ coord,
    const float* __restrict__ anchor_feat, const float* __restrict__ anchor_coord,
    const float* __restrict__ W1, const float* __restrict__ b1,
    const float* __restrict__ g1, const float* __restrict__ be1,
    const float* __restrict__ W2, const float* __restrict__ b2,
    const float* __restrict__ g2, const float* __restrict__ be2,
    const int* __restrict__ maxnorm, const int* __restrict__ idxbuf,
    float* __restrict__ out)
{
    __shared__ __align__(16) float xst[CIN * KNB];   // x transposed: [j][k]
    __shared__ __align__(16) float h1t[H1 * 36];     // h1 transposed: [ch][k], pad to 36
    __shared__ int   sel[KNB];
    __shared__ float pmax[4 * H2];

    const int anchor = blockIdx.x;
    const int b  = anchor >> 11;
    const int mi = anchor & (MM - 1);
    const int tid = threadIdx.x;

    if (tid < KNB) sel[tid] = idxbuf[anchor * KNB + tid];
    __syncthreads();

    const float mn = __int_as_float(maxnorm[b]);

    // build x^T: rows j (3 delta + 64 feat), cols k (neighbors)
    for (int t = tid; t < CIN * KNB; t += 256) {
        int j = t >> 5, k = t & 31;
        int nj = sel[k];
        float vv;
        if (j < 3) {
            float d = __fsub_rn(coord[((size_t)b * NN + nj) * 3 + j],
                                anchor_coord[((size_t)b * MM + mi) * 3 + j]);
            vv = __fdiv_rn(d, mn);
        } else {
            vv = feat[((size_t)b * NN + nj) * CC + (j - 3)]
               - anchor_feat[((size_t)b * MM + mi) * CC + (j - 3)];
        }
        xst[t] = vv;
    }
    __syncthreads();

    const int w = tid >> 6, lane = tid & 63;
    const int k0 = w * 8;   // this wave owns rows k0..k0+7; channel = lane

    // ---- stage 1: h1 = relu(LN(x @ W1 + b1)) ----
    const float bias1 = b1[lane];
    float acc[8];
    #pragma unroll
    for (int kk = 0; kk < 8; kk++) acc[kk] = bias1;
    #pragma unroll 4
    for (int j = 0; j < CIN; j++) {
        float wv = W1[j * H1 + lane];
        const float4 xa = *(const float4*)&xst[j * KNB + k0];
        const float4 xb = *(const float4*)&xst[j * KNB + k0 + 4];
        acc[0] = fmaf(xa.x, wv, acc[0]);
        acc[1] = fmaf(xa.y, wv, acc[1]);
        acc[2] = fmaf(xa.z, wv, acc[2]);
        acc[3] = fmaf(xa.w, wv, acc[3]);
        acc[4] = fmaf(xb.x, wv, acc[4]);
        acc[5] = fmaf(xb.y, wv, acc[5]);
        acc[6] = fmaf(xb.z, wv, acc[6]);
        acc[7] = fmaf(xb.w, wv, acc[7]);
    }
    const float g1v = g1[lane], be1v = be1[lane];
    #pragma unroll
    for (int kk = 0; kk < 8; kk++) {
        float vv = acc[kk];
        float s = vv, s2 = vv * vv;
        #pragma unroll
        for (int off = 32; off; off >>= 1) { s += __shfl_xor(s, off); s2 += __shfl_xor(s2, off); }
        float mu  = s  * (1.0f / H1);
        float var = s2 * (1.0f / H1) - mu * mu;
        float r = rsqrtf(var + 1e-6f);
        float y = fmaf((vv - mu) * r, g1v, be1v);
        h1t[lane * 36 + k0 + kk] = fmaxf(y, 0.0f);
    }
    __syncthreads();

    // ---- stage 2: h2 = relu(LN(h1 @ W2 + b2)), maxpool over k ----
    const float bias2a = b2[lane], bias2b = b2[lane + 64];
    float a[16];
    #pragma unroll
    for (int kk = 0; kk < 8; kk++) { a[kk] = bias2a; a[8 + kk] = bias2b; }
    #pragma unroll 4
    for (int j = 0; j < H1; j++) {
        float w0 = W2[j * H2 + lane];
        float w1 = W2[j * H2 + lane + 64];
        const float4 ha = *(const float4*)&h1t[j * 36 + k0];
        const float4 hb = *(const float4*)&h1t[j * 36 + k0 + 4];
        a[0] = fmaf(ha.x, w0, a[0]);   a[8]  = fmaf(ha.x, w1, a[8]);
        a[1] = fmaf(ha.y, w0, a[1]);   a[9]  = fmaf(ha.y, w1, a[9]);
        a[2] = fmaf(ha.z, w0, a[2]);   a[10] = fmaf(ha.z, w1, a[10]);
        a[3] = fmaf(ha.w, w0, a[3]);   a[11] = fmaf(ha.w, w1, a[11]);
        a[4] = fmaf(hb.x, w0, a[4]);   a[12] = fmaf(hb.x, w1, a[12]);
        a[5] = fmaf(hb.y, w0, a[5]);   a[13] = fmaf(hb.y, w1, a[13]);
        a[6] = fmaf(hb.z, w0, a[6]);   a[14] = fmaf(hb.z, w1, a[14]);
        a[7] = fmaf(hb.w, w0, a[7]);   a[15] = fmaf(hb.w, w1, a[15]);
    }
    const float g2a = g2[lane], g2b = g2[lane + 64];
    const float be2a = be2[lane], be2b = be2[lane + 64];
    float mx0 = -INFINITY, mx1 = -INFINITY;
    #pragma unroll
    for (int kk = 0; kk < 8; kk++) {
        float a0 = a[kk], a1 = a[8 + kk];
        float s = a0 + a1, s2 = a0 * a0 + a1 * a1;
        #pragma unroll
        for (int off = 32; off; off >>= 1) { s += __shfl_xor(s, off); s2 += __shfl_xor(s2, off); }
        float mu  = s  * (1.0f / H2);
        float var = s2 * (1.0f / H2) - mu * mu;
        float r = rsqrtf(var + 1e-6f);
        float y0 = fmaxf(fmaf((a0 - mu) * r, g2a, be2a), 0.0f);
        float y1 = fmaxf(fmaf((a1 - mu) * r, g2b, be2b), 0.0f);
        mx0 = fmaxf(mx0, y0);
        mx1 = fmaxf(mx1, y1);
    }
    pmax[w * H2 + lane]      = mx0;
    pmax[w * H2 + lane + 64] = mx1;
    __syncthreads();
    if (tid < H2) {
        float vv = pmax[tid];
        #pragma unroll
        for (int ww = 1; ww < 4; ww++) vv = fmaxf(vv, pmax[ww * H2 + tid]);
        out[(size_t)anchor * H2 + tid] = vv;
    }
}

extern "C" void kernel_launch(void* const* d_in, const int* in_sizes, int n_in,
                              void* d_out, int out_size, void* d_ws, size_t ws_size,
                              hipStream_t stream) {
    const float* feat         = (const float*)d_in[0];
    const float* coord        = (const float*)d_in[1];
    const float* anchor_feat  = (const float*)d_in[2];
    const float* anchor_coord = (const float*)d_in[3];
    const float* W1  = (const float*)d_in[4];
    const float* b1  = (const float*)d_in[5];
    const float* g1  = (const float*)d_in[6];
    const float* be1 = (const float*)d_in[7];
    const float* W2  = (const float*)d_in[8];
    const float* b2  = (const float*)d_in[9];
    const float* g2  = (const float*)d_in[10];
    const float* be2 = (const float*)d_in[11];
    float* out = (float*)d_out;

    int* maxn   = (int*)d_ws;        // 4 ints
    int* idxbuf = (int*)d_ws + 16;   // [BB*MM*KNB]

    init_kernel<<<1, 64, 0, stream>>>(maxn);
    knn_kernel<<<BB * MM, 256, 0, stream>>>(coord, anchor_coord, idxbuf, maxn);
    mlp_kernel<<<BB * MM, 256, 0, stream>>>(feat, coord, anchor_feat, anchor_coord,
                                            W1, b1, g1, be1, W2, b2, g2, be2,
                                            maxn, idxbuf, out);
}